// Round 8
// baseline (297.829 us; speedup 1.0000x reference)
//
#include <hip/hip_runtime.h>

typedef unsigned short u16;
typedef unsigned int u32;
typedef __attribute__((ext_vector_type(8))) short short8;
typedef __attribute__((ext_vector_type(4))) float f32x4;

#define N_NODES 16384
#define B_MOL   256
#define NPM     64
#define E_EDGES 65536
#define FMAXF   32
#define AMAXA   16
#define HID     960
#define NFG     205
#define BF_ROWS 8192
#define OUT1    7864320   // B*FMAX*HID
#define NTOT    4516800   // total normalized elements

__device__ __forceinline__ float bf2f(u16 u){ u32 x=((u32)u)<<16; float f; __builtin_memcpy(&f,&x,4); return f; }
__device__ __forceinline__ u16 f2bf(float f){ u32 x; __builtin_memcpy(&x,&f,4); x += 0x7FFFu + ((x>>16)&1u); return (u16)(x>>16); }

__device__ __forceinline__ void gload_lds16(const u16* g, u16* l){
    __builtin_amdgcn_global_load_lds(
        (const __attribute__((address_space(1))) void*)g,
        (__attribute__((address_space(3))) void*)l, 16, 0, 0);
}
// swizzled fragment-region address (16-row x 32-col regions of a 960-col matrix)
__device__ __forceinline__ size_t swzA(int row, int col){      // col multiple of 8, u16 units
    return ((size_t)((row>>4)*30 + (col>>5)))*512 + (size_t)(((((col>>3)&3)*16) + (row&15))*8);
}
__device__ __forceinline__ size_t swzE(int row, int col){      // element-granular
    return ((size_t)((row>>4)*30 + (col>>5)))*512 + (size_t)((((col>>3)&3)*16 + (row&15))*8 + (col&7));
}

struct NormSrcs { const void* p[11]; };
// all 11 float tensors -> contiguous bf16 region; per-block dtype flag; b2f/projbf fp32; zero deg + bias-accum
__global__ __launch_bounds__(256) void k_normAll(NormSrcs s, u16* __restrict__ region,
                                                 float* __restrict__ b2f, float* __restrict__ projbf,
                                                 float* __restrict__ z4, int* __restrict__ flag,
                                                 int* __restrict__ deg){
    __shared__ int cnt;
    int t = threadIdx.x;
    if (t==0) cnt = 0;
    __syncthreads();
    u16 pv = ((const u16*)s.p[0])[t*2];
    if (((pv>>7)&0xFF) >= 0xC0) atomicAdd(&cnt, 1);
    __syncthreads();
    int fl = (cnt > 16) ? 1 : 0;              // 1 => inputs are fp32
    int i = blockIdx.x*256 + t;
    if (blockIdx.x==0 && t==0) *flag = fl;
    if (i < N_NODES) deg[i] = 0;
    if (i < 4*HID) z4[i] = 0.f;
    if (i >= NTOT) return;
    int seg, off;
    if      (i <   81920){seg=0;  off=i;}
    else if (i <   86720){seg=1;  off=i-81920;}
    else if (i <   87680){seg=2;  off=i-86720;}
    else if (i < 1009280){seg=3;  off=i-87680;}
    else if (i < 1010240){seg=4;  off=i-1009280;}
    else if (i < 1115200){seg=5;  off=i-1010240;}
    else if (i < 1135680){seg=6;  off=i-1115200;}
    else if (i < 2057280){seg=7;  off=i-1135680;}
    else if (i < 2058240){seg=8;  off=i-2057280;}
    else if (i < 4515840){seg=9;  off=i-2058240;}
    else                 {seg=10; off=i-4515840;}
    const void* sp = s.p[seg];
    float fv; u16 uv;
    if (fl){ fv = ((const float*)sp)[off]; uv = f2bf(fv); }
    else   { uv = ((const u16*)sp)[off];  fv = bf2f(uv); }
    region[i] = uv;
    if (seg==4) b2f[off] = fv;
    if (seg==8) projbf[off] = fv;
}

// ================= device bodies =================

__device__ __forceinline__ void gemm_sq(int bx, int by, const u16* __restrict__ A, int lda,
                                        const u16* __restrict__ Bt, int ldb,
                                        u16* __restrict__ C, int swz, char* smem)
{
    u16* As = (u16*)smem;            // 64*40
    u16* Bs = (u16*)smem + 64*40;
    const int tid = threadIdx.x;
    const int wave = tid>>6, lane = tid&63;
    const int wm = wave>>1, wn = wave&1;
    const int q = lane>>4, l16 = lane&15;
    const int m0 = bx*64, n0 = by*64;
    const int sm = tid>>2, sk = (tid&3)*8;
    f32x4 acc00={0,0,0,0}, acc01={0,0,0,0}, acc10={0,0,0,0}, acc11={0,0,0,0};
    const u16* Ap = A + (size_t)(m0+sm)*lda + sk;
    const u16* Bp = Bt + (size_t)(n0+sm)*ldb + sk;
    for (int k0=0; k0<HID; k0+=32){
        short8 av = *(const short8*)(Ap + k0);
        short8 bv = *(const short8*)(Bp + k0);
        *(short8*)(As + sm*40 + sk) = av;
        *(short8*)(Bs + sm*40 + sk) = bv;
        __syncthreads();
        short8 a0 = *(const short8*)(As + (wm*32      + l16)*40 + q*8);
        short8 a1 = *(const short8*)(As + (wm*32 + 16 + l16)*40 + q*8);
        short8 b0 = *(const short8*)(Bs + (wn*32      + l16)*40 + q*8);
        short8 b1 = *(const short8*)(Bs + (wn*32 + 16 + l16)*40 + q*8);
        acc00 = __builtin_amdgcn_mfma_f32_16x16x32_bf16(a0,b0,acc00,0,0,0);
        acc01 = __builtin_amdgcn_mfma_f32_16x16x32_bf16(a0,b1,acc01,0,0,0);
        acc10 = __builtin_amdgcn_mfma_f32_16x16x32_bf16(a1,b0,acc10,0,0,0);
        acc11 = __builtin_amdgcn_mfma_f32_16x16x32_bf16(a1,b1,acc11,0,0,0);
        __syncthreads();
    }
    #pragma unroll
    for (int i=0;i<2;i++){
        int rowb = m0 + wm*32 + i*16 + q*4;
        #pragma unroll
        for (int j=0;j<2;j++){
            int col = n0 + wn*32 + j*16 + l16;
            f32x4 av = (i==0) ? ((j==0)?acc00:acc01) : ((j==0)?acc10:acc11);
            #pragma unroll
            for (int r=0;r<4;r++){
                int row = rowb + r;
                u16 o = f2bf(av[r]);
                if (swz) C[swzE(row,col)] = o;
                else     C[(size_t)row*HID + col] = o;
            }
        }
    }
}
__device__ __forceinline__ void gemm64f(int bx, int by, const u16* __restrict__ A, int lda,
                                        const u16* __restrict__ Bt, int ldb,
                                        float* __restrict__ C, int M, int K,
                                        const float* __restrict__ addv, char* smem)
{
    u16* As = (u16*)smem;
    u16* Bs = (u16*)smem + 64*40;
    const int tid = threadIdx.x;
    const int wave = tid>>6, lane = tid&63;
    const int wm = wave>>1, wn = wave&1;
    const int q = lane>>4, l16 = lane&15;
    const int m0 = bx*64, n0 = by*64;
    const int sm = tid>>2, sk = (tid&3)*8;
    f32x4 acc00={0,0,0,0}, acc01={0,0,0,0}, acc10={0,0,0,0}, acc11={0,0,0,0};
    const bool aOk = (m0+sm) < M;
    const u16* Ap = A + (size_t)(m0+sm)*lda + sk;
    const u16* Bp = Bt + (size_t)(n0+sm)*ldb + sk;
    for (int k0=0; k0<K; k0+=32){
        short8 av = {0,0,0,0,0,0,0,0};
        if (aOk) av = *(const short8*)(Ap + k0);
        short8 bv = *(const short8*)(Bp + k0);
        *(short8*)(As + sm*40 + sk) = av;
        *(short8*)(Bs + sm*40 + sk) = bv;
        __syncthreads();
        short8 a0 = *(const short8*)(As + (wm*32      + l16)*40 + q*8);
        short8 a1 = *(const short8*)(As + (wm*32 + 16 + l16)*40 + q*8);
        short8 b0 = *(const short8*)(Bs + (wn*32      + l16)*40 + q*8);
        short8 b1 = *(const short8*)(Bs + (wn*32 + 16 + l16)*40 + q*8);
        acc00 = __builtin_amdgcn_mfma_f32_16x16x32_bf16(a0,b0,acc00,0,0,0);
        acc01 = __builtin_amdgcn_mfma_f32_16x16x32_bf16(a0,b1,acc01,0,0,0);
        acc10 = __builtin_amdgcn_mfma_f32_16x16x32_bf16(a1,b0,acc10,0,0,0);
        acc11 = __builtin_amdgcn_mfma_f32_16x16x32_bf16(a1,b1,acc11,0,0,0);
        __syncthreads();
    }
    #pragma unroll
    for (int i=0;i<2;i++){
        int rowb = m0 + wm*32 + i*16 + q*4;
        #pragma unroll
        for (int j=0;j<2;j++){
            int col = n0 + wn*32 + j*16 + l16;
            f32x4 av = (i==0) ? ((j==0)?acc00:acc01) : ((j==0)?acc10:acc11);
            float add = addv ? addv[col] : 0.f;
            #pragma unroll
            for (int r=0;r<4;r++){
                int row = rowb + r;
                if (row < M) C[(size_t)row*HID + col] = av[r] + add;
            }
        }
    }
}
__device__ __forceinline__ void transpose_tile(int bx, int by, const u16* __restrict__ src,
                                               u16* __restrict__ dst, int R, int C, char* smem)
{
    u16 (*tl)[33] = (u16(*)[33])smem;
    int c0 = bx*32, r0 = by*32;
    int tx = threadIdx.x & 31, ty = threadIdx.x >> 5;   // 32x8
    #pragma unroll
    for (int i=0;i<4;i++) tl[ty+i*8][tx] = src[(size_t)(r0+ty+i*8)*C + c0+tx];
    __syncthreads();
    #pragma unroll
    for (int i=0;i<4;i++) dst[(size_t)(c0+ty+i*8)*R + r0+tx] = tl[tx][ty+i*8];
}
__device__ __forceinline__ void vecmat_body(int bx, int by, const float* __restrict__ v,
                                            const u16* __restrict__ M, float* __restrict__ out, char* smem)
{
    float (*part)[64] = (float(*)[64])smem;
    int tid = threadIdx.x;
    int cl = tid & 63;
    int c = bx*64 + cl;
    int kg = tid >> 6;
    int k0 = by*60 + kg*15;
    float s = 0.f;
    #pragma unroll
    for (int i=0;i<15;i++) s += v[k0+i]*bf2f(M[(size_t)(k0+i)*HID + c]);
    part[kg][cl] = s;
    __syncthreads();
    if (kg==0) atomicAdd(&out[c], part[0][cl]+part[1][cl]+part[2][cl]+part[3][cl]);
}
__device__ __forceinline__ void scandinv_body(const int* __restrict__ deg, int* __restrict__ off,
                                              int* __restrict__ cur, float* __restrict__ dinv, char* smem)
{
    int* ps = (int*)smem;
    int t = threadIdx.x;
    const int chunk = N_NODES/256; // 64
    int base0 = t*chunk;
    int s = 0;
    for (int i=0;i<chunk;i++) s += deg[base0+i];
    ps[t] = s; __syncthreads();
    for (int ofs=1; ofs<256; ofs<<=1){
        int v = ps[t];
        int add = (t>=ofs) ? ps[t-ofs] : 0;
        __syncthreads();
        ps[t] = v + add;
        __syncthreads();
    }
    int run = (t==0) ? 0 : ps[t-1];
    for (int i=0;i<chunk;i++){
        int d = deg[base0+i];
        off[base0+i]=run; cur[base0+i]=run; run += d;
        dinv[base0+i] = rsqrtf(1.0f + (float)d);
    }
    if (t==255) off[N_NODES] = run;
}

// ================= fused selector kernels =================
__global__ __launch_bounds__(256) void k_L1(const u16* __restrict__ fuseWn, u16* __restrict__ fuseWT,
                                            const int* __restrict__ dst, int* __restrict__ deg){
    __shared__ __attribute__((aligned(16))) char smem[2112];
    int b = blockIdx.x;
    if (b < 2400){
        transpose_tile(b%30, b/30, fuseWn, fuseWT, 2560, HID, smem);
    } else {
        int e = (b-2400)*256 + threadIdx.x;
        if (e < E_EDGES) atomicAdd(&deg[dst[e]], 1);
    }
}
__global__ __launch_bounds__(256) void k_L2(const u16* fuseWT, const u16* projWn, const u16* W2n,
                                            u16* Ub, u16* WglobT,
                                            const int* deg, int* off, int* cur, float* dinv){
    __shared__ __attribute__((aligned(16))) char smem[10240];
    int b = blockIdx.x;
    if (b < 450){
        int z = b/225, r = b%225;
        if (z==0) gemm_sq(r%15, r/15, fuseWT+640, 2560, projWn, HID, Ub, 0, smem);
        else      gemm_sq(r%15, r/15, fuseWT+1600, 2560, W2n, HID, WglobT, 0, smem);
    } else {
        scandinv_body(deg, off, cur, dinv, smem);
    }
}
__global__ __launch_bounds__(256) void k_L3(const u16* Ub, const u16* W2n, u16* WbigS,
                                            const u16* fgeN, const u16* posN, const u16* fuseWT,
                                            float* fgA, float* pWbM,
                                            const int* src, const int* dst, const float* dinv,
                                            int* cur, int* csr_s, float* csr_w){
    __shared__ __attribute__((aligned(16))) char smem[10240];
    int b = blockIdx.x;
    if (b < 225){
        gemm_sq(b%15, b/15, Ub, HID, W2n, HID, WbigS, 1, smem);
    } else if (b < 300){
        int bb = b-225;
        if (bb < 60) gemm64f(bb%4, bb/4, fgeN, 512, fuseWT, 2560, fgA, NFG, 512, nullptr, smem);
        else         gemm64f(0, bb-60, posN, 128, fuseWT+512, 2560, pWbM, FMAXF, 128, nullptr, smem);
    } else {
        int e = (b-300)*256 + threadIdx.x;
        if (e < E_EDGES){
            int s = src[e], d = dst[e];
            int p = atomicAdd(&cur[d], 1);
            csr_s[p] = s;
            csr_w[p] = dinv[s]*dinv[d];
        }
    }
}
__global__ __launch_bounds__(256) void k_L4(const u16* __restrict__ gxn, const float* __restrict__ dinv,
                                            const int* __restrict__ off, const int* __restrict__ csr_s,
                                            const float* __restrict__ csr_w,
                                            const u16* __restrict__ W1, const u16* __restrict__ b1,
                                            u16* __restrict__ h1b,
                                            const float* b2f, const float* projbf, const u16* fuseWn,
                                            const u16* projWn, float* tvb, float* cC, float* gvec){
    __shared__ __attribute__((aligned(16))) char smem[1024];
    int b = blockIdx.x;
    if (b < 8192){
        float* a2 = (float*)smem;     // [2][8]
        int t = threadIdx.x;
        int h = t>>7, tl = t&127;
        int n = b*2 + h;
        if (tl < 5){
            int k = tl;
            float di = dinv[n], sw = di*di;
            float a = sw * bf2f(gxn[n*5+k]);
            int j0 = off[n], j1 = off[n+1];
            for (int j=j0;j<j1;j++) a += csr_w[j]*bf2f(gxn[csr_s[j]*5+k]);
            a2[h*8+k] = a;
        }
        __syncthreads();
        if (tl < 120){
            int c8 = tl*8;
            float a[5];
            #pragma unroll
            for (int k=0;k<5;k++) a[k] = a2[h*8+k];
            float r[8];
            short8 bb = *(const short8*)(b1 + c8);
            #pragma unroll
            for (int j=0;j<8;j++) r[j] = bf2f(((u16*)&bb)[j]);
            #pragma unroll
            for (int k=0;k<5;k++){
                short8 wv = *(const short8*)(W1 + k*HID + c8);
                #pragma unroll
                for (int j=0;j<8;j++) r[j] += a[k]*bf2f(((u16*)&wv)[j]);
            }
            short8 o;
            #pragma unroll
            for (int j=0;j<8;j++) ((u16*)&o)[j] = f2bf(fmaxf(r[j],0.f));
            *(short8*)(h1b + (size_t)n*HID + c8) = o;
        }
    } else {
        int bb = b - 8192;
        int z = bb/240, r = bb%240;
        if (z==0)      vecmat_body(r%15, r/15, b2f,    projWn,            tvb,  smem);
        else if (z==1) vecmat_body(r%15, r/15, projbf, fuseWn + 640*HID,  cC,   smem);
        else           vecmat_body(r%15, r/15, b2f,    fuseWn + 1600*HID, gvec, smem);
    }
}
__global__ __launch_bounds__(256) void k_L5(const u16* __restrict__ h1b, const float* __restrict__ dinv,
                                            const int* __restrict__ off, const int* __restrict__ csr_s,
                                            const float* __restrict__ csr_w, u16* __restrict__ P1b,
                                            const float* tvb, const u16* fuseWn, float* vb,
                                            const float* cC, const float* gvec, const u16* fusebn, float* c0){
    __shared__ __attribute__((aligned(16))) char smem[1024];
    int b = blockIdx.x;
    if (b < 4096){
        int wv = threadIdx.x>>6, lane = threadIdx.x&63;
        int n = b*4 + wv;
        int c = lane*16;
        bool act = lane < 60;
        float di = dinv[n], sw = di*di;
        float acc[16];
        if (act){
            short8 h0 = *(const short8*)(h1b + (size_t)n*HID + c);
            short8 h1v = *(const short8*)(h1b + (size_t)n*HID + c + 8);
            #pragma unroll
            for (int j=0;j<8;j++){ acc[j] = sw*bf2f(((u16*)&h0)[j]); acc[8+j] = sw*bf2f(((u16*)&h1v)[j]); }
        } else {
            #pragma unroll
            for (int j=0;j<16;j++) acc[j] = 0.f;
        }
        int j0 = off[n], j1 = off[n+1];
        for (int j=j0;j<j1;j++){
            int s = csr_s[j]; float w = csr_w[j];
            if (act){
                short8 v0 = *(const short8*)(h1b + (size_t)s*HID + c);
                short8 v1 = *(const short8*)(h1b + (size_t)s*HID + c + 8);
                #pragma unroll
                for (int j2=0;j2<8;j2++){ acc[j2] += w*bf2f(((u16*)&v0)[j2]); acc[8+j2] += w*bf2f(((u16*)&v1)[j2]); }
            }
        }
        if (act){
            short8 o0, o1;
            #pragma unroll
            for (int j=0;j<8;j++){ ((u16*)&o0)[j] = f2bf(acc[j]); ((u16*)&o1)[j] = f2bf(acc[8+j]); }
            *(short8*)(P1b + (size_t)n*HID + c) = o0;
            *(short8*)(P1b + (size_t)n*HID + c + 8) = o1;
        }
    } else if (b < 4336){
        int bb = b - 4096;
        vecmat_body(bb%15, bb/15, tvb, fuseWn + 640*HID, vb, smem);
    } else {
        int c = (b-4336)*256 + threadIdx.x;
        if (c < HID) c0[c] = cC[c] + gvec[c] + bf2f(fusebn[c]);
    }
}
__global__ __launch_bounds__(256) void k_L6(const u16* __restrict__ P1b, const int* __restrict__ fgi,
                                            const int* __restrict__ ptr, u16* __restrict__ prb,
                                            float* __restrict__ evec, u16* __restrict__ maskb,
                                            float* __restrict__ maskf, const int* __restrict__ flag,
                                            u16* __restrict__ gmb){
    int b = blockIdx.x;
    if (b < 2048){
        int wv = threadIdx.x>>6, lane = threadIdx.x&63;
        int bf = b*4 + wv;
        int mb = bf >> 5;
        int base = ptr[mb];
        int c = lane*16;
        bool act = lane < 60;
        float acc[16];
        #pragma unroll
        for (int j=0;j<16;j++) acc[j] = 0.f;
        int cnt = 0;
        #pragma unroll
        for (int a=0;a<AMAXA;a++){
            int idx = fgi[bf*AMAXA + a];
            if (idx >= 0){
                cnt++;
                if (act){
                    short8 v0 = *(const short8*)(P1b + (size_t)(base+idx)*HID + c);
                    short8 v1 = *(const short8*)(P1b + (size_t)(base+idx)*HID + c + 8);
                    #pragma unroll
                    for (int j=0;j<8;j++){ acc[j] += bf2f(((u16*)&v0)[j]); acc[8+j] += bf2f(((u16*)&v1)[j]); }
                }
            }
        }
        float inv = (cnt>0) ? 1.0f/(float)cnt : 0.0f;
        if (act){
            short8 o0, o1;
            #pragma unroll
            for (int j=0;j<8;j++){ ((u16*)&o0)[j] = f2bf(acc[j]*inv); ((u16*)&o1)[j] = f2bf(acc[8+j]*inv); }
            *(short8*)(prb + swzA(bf, c)) = o0;
            *(short8*)(prb + swzA(bf, c+8)) = o1;
        }
        if (lane == 0){
            float e = (cnt>0) ? 1.0f : 0.0f;
            evec[bf] = e;
            if (*flag) maskf[bf] = e;
            else       maskb[bf] = f2bf(e);
        }
    } else {
        int id = (b-2048)*256 + threadIdx.x;   // 256 mol * 120 c8
        int mb = id / 120; int c8 = (id - mb*120)*8;
        float s[8] = {0,0,0,0,0,0,0,0};
        for (int i=0;i<NPM;i++){
            short8 v = *(const short8*)(P1b + (size_t)(mb*NPM+i)*HID + c8);
            #pragma unroll
            for (int j=0;j<8;j++) s[j] += bf2f(((u16*)&v)[j]);
        }
        const float inv = 1.0f/(float)NPM;
        short8 o;
        #pragma unroll
        for (int j=0;j<8;j++) ((u16*)&o)[j] = f2bf(s[j]*inv);
        *(short8*)(gmb + (size_t)mb*HID + c8) = o;
    }
}
__global__ __launch_bounds__(256) void k_L7(const u16* gmb, const u16* WglobT, float* Gc, const float* c0){
    __shared__ __attribute__((aligned(16))) char smem[10240];
    int b = blockIdx.x;
    gemm64f(b%4, b/4, gmb, HID, WglobT, HID, Gc, B_MOL, HID, c0, smem);
}

// L8 final GEMM: out[8192,960] = prb @ WbigS^T + epilogue
// 512 threads / 8 waves (4x2 wave grid), BM=128 BN=96 BK=64, single-buffer swizzled staging
// grid 64x10 = 640 blocks -> 2.5 blocks/CU x 8 waves = 20 waves/CU
__global__ __launch_bounds__(512) void k_gemmF(
    const u16* __restrict__ A, const u16* __restrict__ Bt,
    float* __restrict__ Cf, u16* __restrict__ Cb,
    const int* __restrict__ fg_type, const float* __restrict__ evec,
    const float* __restrict__ fgA, const float* __restrict__ pWbM,
    const float* __restrict__ vb, const float* __restrict__ Gc,
    const int* __restrict__ flag)
{
    __shared__ __attribute__((aligned(16))) u16 SA[16*512];   // region a = rowreg*2 + kk
    __shared__ __attribute__((aligned(16))) u16 SB[12*512];   // region b = colreg*2 + kk
    const int tid = threadIdx.x;
    const int wave = tid>>6, lane = tid&63;
    const int wm = wave>>1, wn = wave&1;      // 4 x 2 wave grid
    const int q = lane>>4, l16 = lane&15;
    const int m0 = blockIdx.x*128, n0 = blockIdx.y*96;
    const int R0 = blockIdx.x*8, N0 = blockIdx.y*6;

    f32x4 acc[2][3];
    #pragma unroll
    for (int i=0;i<2;i++)
        #pragma unroll
        for (int j=0;j<3;j++) acc[i][j] = (f32x4){0,0,0,0};

    const u16* gA = A + lane*8;
    const u16* gB = Bt + lane*8;
    const int a0 = wave*2, a1 = wave*2+1;     // A regions this wave stages (16 total)
    const int b0 = wave*2, b1 = wave*2+1;     // B regions (12 total, waves 0..5)

    for (int s=0; s<15; s++){
        int kb = s*2;
        gload_lds16(gA + ((size_t)((R0+(a0>>1))*30 + kb + (a0&1)))*512, SA + a0*512);
        gload_lds16(gA + ((size_t)((R0+(a1>>1))*30 + kb + (a1&1)))*512, SA + a1*512);
        if (wave < 6){
            gload_lds16(gB + ((size_t)((N0+(b0>>1))*30 + kb + (b0&1)))*512, SB + b0*512);
            gload_lds16(gB + ((size_t)((N0+(b1>>1))*30 + kb + (b1&1)))*512, SB + b1*512);
        }
        __syncthreads();
        short8 af[2][2], bfr[3][2];
        #pragma unroll
        for (int i=0;i<2;i++)
            #pragma unroll
            for (int kk=0;kk<2;kk++)
                af[i][kk] = *(const short8*)(SA + (((wm*2+i)*2+kk)*512 + lane*8));
        #pragma unroll
        for (int j=0;j<3;j++)
            #pragma unroll
            for (int kk=0;kk<2;kk++)
                bfr[j][kk] = *(const short8*)(SB + (((wn*3+j)*2+kk)*512 + lane*8));
        #pragma unroll
        for (int i=0;i<2;i++)
            #pragma unroll
            for (int j=0;j<3;j++){
                acc[i][j] = __builtin_amdgcn_mfma_f32_16x16x32_bf16(af[i][0], bfr[j][0], acc[i][j], 0,0,0);
                acc[i][j] = __builtin_amdgcn_mfma_f32_16x16x32_bf16(af[i][1], bfr[j][1], acc[i][j], 0,0,0);
            }
        __syncthreads();
    }

    const int isf = *flag;
    #pragma unroll
    for (int i=0;i<2;i++){
        int rowb = m0 + wm*32 + i*16 + q*4;
        #pragma unroll
        for (int r=0;r<4;r++){
            int row = rowb + r;
            int bb = row>>5, ff = row&31;
            int ty = fg_type[row];
            float e = evec[row];
            #pragma unroll
            for (int j=0;j<3;j++){
                int col = n0 + wn*48 + j*16 + l16;
                float v = acc[i][j][r]
                        + fgA[ty*HID+col] + pWbM[ff*HID+col]
                        + e*vb[col] + Gc[bb*HID+col];
                if (isf) Cf[(size_t)row*HID + col] = v;
                else     Cb[(size_t)row*HID + col] = f2bf(v);
            }
        }
    }
}

extern "C" void kernel_launch(void* const* d_in, const int* in_sizes, int n_in,
                              void* d_out, int out_size, void* d_ws, size_t ws_size,
                              hipStream_t stream) {
    const int* edge_idx  = (const int*)d_in[1];
    const int* ptr       = (const int*)d_in[3];
    const int* fg_type   = (const int*)d_in[4];
    const int* fg_idx    = (const int*)d_in[5];

    // ---- workspace layout ----
    char* w = (char*)d_ws;
    auto nxt = [&](size_t b)->char*{ char* p = w; w += (b + 255) & ~(size_t)255; return p; };
    u16* big0   = (u16*)nxt((size_t)N_NODES*HID*2);       // fuseWT+Ub -> h1b -> prb(swizzled)
    u16* fuseWT = big0;
    u16* Ub     = big0 + (size_t)HID*2560;
    u16* h1b    = big0;
    u16* prb    = big0;
    u16* P1b    = (u16*)nxt((size_t)N_NODES*HID*2);
    u16*  WbigS  = (u16*) nxt((size_t)HID*HID*2);
    u16*  WglobT = (u16*) nxt((size_t)HID*HID*2);
    float* fgA   = (float*)nxt((size_t)NFG*HID*4);
    float* pWbM  = (float*)nxt((size_t)FMAXF*HID*4);
    float* b2f   = (float*)nxt(HID*4);
    float* projbf= (float*)nxt(HID*4);
    float* tvb   = (float*)nxt(HID*4);   // tvb,cC,gvec,vb contiguous 4*HID zero-block
    float* cC    = (float*)nxt(HID*4);
    float* gvec  = (float*)nxt(HID*4);
    float* vb    = (float*)nxt(HID*4);
    float* c0    = (float*)nxt(HID*4);
    int*   deg   = (int*)  nxt(N_NODES*4);
    float* dinv  = (float*)nxt(N_NODES*4);
    int*   off   = (int*)  nxt((N_NODES+1)*4);
    int*   cur   = (int*)  nxt(N_NODES*4);
    int*   csr_s = (int*)  nxt(E_EDGES*4);
    float* csr_w = (float*)nxt(E_EDGES*4);
    float* evec  = (float*)nxt(BF_ROWS*4);
    u16*   gmb   = (u16*)  nxt((size_t)B_MOL*HID*2);
    float* Gc    = (float*)nxt((size_t)B_MOL*HID*4);
    int*   flag  = (int*)  nxt(256);
    u16*   region= (u16*)  nxt((size_t)NTOT*2);
    // views into region
    u16* gxn    = region;
    u16* W1n    = region +   81920;
    u16* b1n    = region +   86720;
    u16* W2n    = region +   87680;
    u16* fgeN   = region + 1010240;
    u16* posN   = region + 1115200;
    u16* projWn = region + 1135680;
    u16* fuseWn = region + 2058240;
    u16* fusebn = region + 4515840;

    NormSrcs ns;
    ns.p[0]=d_in[0]; ns.p[1]=d_in[6]; ns.p[2]=d_in[7]; ns.p[3]=d_in[8]; ns.p[4]=d_in[9];
    ns.p[5]=d_in[10]; ns.p[6]=d_in[11]; ns.p[7]=d_in[12]; ns.p[8]=d_in[13]; ns.p[9]=d_in[14]; ns.p[10]=d_in[15];
    k_normAll<<<(NTOT+255)/256,256,0,stream>>>(ns, region, b2f, projbf, tvb, flag, deg);
    k_L1<<<2656,256,0,stream>>>(fuseWn, fuseWT, edge_idx + E_EDGES, deg);
    k_L2<<<451,256,0,stream>>>(fuseWT, projWn, W2n, Ub, WglobT, deg, off, cur, dinv);
    k_L3<<<556,256,0,stream>>>(Ub, W2n, WbigS, fgeN, posN, fuseWT, fgA, pWbM,
                               edge_idx, edge_idx + E_EDGES, dinv, cur, csr_s, csr_w);
    k_L4<<<8912,256,0,stream>>>(gxn, dinv, off, csr_s, csr_w, W1n, b1n, h1b,
                                b2f, projbf, fuseWn, projWn, tvb, cC, gvec);
    k_L5<<<4340,256,0,stream>>>(h1b, dinv, off, csr_s, csr_w, P1b,
                                tvb, fuseWn, vb, cC, gvec, fusebn, c0);
    k_L6<<<2168,256,0,stream>>>(P1b, fg_idx, ptr, prb, evec,
                                (u16*)d_out + OUT1, (float*)d_out + OUT1, flag, gmb);
    k_L7<<<60,256,0,stream>>>(gmb, WglobT, Gc, c0);
    k_gemmF<<<dim3(64,10),512,0,stream>>>(prb, WbigS, (float*)d_out, (u16*)d_out,
                                          fg_type, evec, fgA, pWbM, vb, Gc, flag);
    (void)in_sizes; (void)n_in; (void)out_size; (void)ws_size;
}